// Round 7
// baseline (89.755 us; speedup 1.0000x reference)
//
#include <hip/hip_runtime.h>

typedef unsigned short u16;
typedef unsigned int u32;
typedef __attribute__((ext_vector_type(8))) short bf16x8;
typedef __attribute__((ext_vector_type(4))) float f32x4;
typedef __attribute__((ext_vector_type(4))) unsigned short u16x4;

#define DEVI __device__ __forceinline__

constexpr float L2GAMMA = -0.15200309344504997f; // log2(0.9)
constexpr float INV_SQRT_H = 0.0625f;            // 1/sqrt(256)

DEVI u16 f2bf(float x) {
  union { float f; unsigned u; } v; v.f = x;
  unsigned r = v.u + 0x7FFFu + ((v.u >> 16) & 1u);
  return (u16)(r >> 16);
}

DEVI u32 pack2bf(float f0, float f1) {
  u32 u0 = __float_as_uint(f0) + 0x8000u;
  u32 u1 = __float_as_uint(f1) + 0x8000u;
  return __builtin_amdgcn_perm(u1, u0, 0x07060302u); // [f1.hi16 : f0.hi16]
}

// ---- kernel 0: W_Q|W_K|W_V (each 256x1024 fp32) -> Wb[768][1024] bf16 ----
__global__ void cvt_w_kernel(const float4* __restrict__ wq, const float4* __restrict__ wk,
                             const float4* __restrict__ wv, u16x4* __restrict__ dst) {
  int i = blockIdx.x * blockDim.x + threadIdx.x; // 0..196607
  int w = i >> 16, off = i & 65535;
  const float4* s = (w == 0) ? wq : ((w == 1) ? wk : wv);
  float4 v = s[off];
  u16x4 o; o.x = f2bf(v.x); o.y = f2bf(v.y); o.z = f2bf(v.z); o.w = f2bf(v.w);
  dst[(w << 16) + off] = o;
}

// ---- kernel 1: fused QKV GEMM  C[16384x768] = x[16384x1024](fp32)*Wb^T ---
// BM=64, BN=768 (FULL N), BK=32, 512 thr (8 waves, wave tile 64x96).
// Grid 256 = 1 WG/CU exactly (152 KB LDS forbids co-residency -> full spread).
// x read ONCE (fp32, fused cvt); W L2-resident; B-staging L2-bound ~11 us.
// B: 3-buffer rotation, gload_lds, stage(t+2) issued BEFORE compute(t),
//    counted vmcnt(7) at iter end (never 0 until tail).   [T3+T4]
// A: fp32->bf16 in regs (2-gen ping-pong aS0/aS1, static), ds_write, 2-buf.
// Swizzle (64B rows, 4x16B slots): slot' = slot ^ ((row>>1)&3); reads and
// writes are <=2-way (free). gload_lds: linear LDS dest + pre-swizzled
// global source (rule 21).
__global__ __launch_bounds__(512, 2) void qkv_gemm_kernel(const float* __restrict__ Xf, const u16* __restrict__ Wb,
                                                          u16* __restrict__ Qb, u16* __restrict__ Kb,
                                                          u16* __restrict__ Vt) {
  __shared__ u16 Blds[3][24576];   // 3 x 768x32 bf16 = 147456 B
  __shared__ u16 Alds[2][2048];    // 2 x  64x32 bf16 =   8192 B
  const int bid = blockIdx.x;      // 0..255
  const int m0 = bid << 6;
  const int tid = threadIdx.x;
  const int wid = tid >> 6, lane = tid & 63;
  const int lrow = lane & 15, lkg = lane >> 4;
  // B staging: chunk = 16 rows x 64 B; wave stages chunks wid*6..+5
  const int brow = lane >> 2;                                   // row in chunk
  const int bcol = ((lane & 3) ^ ((lane >> 3) & 3)) << 3;       // elems, pre-swizzled
  // A load/cvt/write: thread -> row tid>>3, float4 col tid&7
  const int arow = tid >> 3, af4 = tid & 7;
  const float* aload = Xf + (size_t)(m0 + arow) * 1024 + af4 * 4;
  const int awr = arow * 32 + ((((af4 >> 1) ^ ((arow >> 1) & 3)) << 3) | ((af4 & 1) << 2));
  // frag read swizzle
  const int sw = (lkg ^ ((lrow >> 1) & 3)) << 3;

#define BSTAGE(T, WB) do { \
  _Pragma("unroll") for (int j_ = 0; j_ < 6; ++j_) { \
    const int c_ = wid * 6 + j_; \
    const u16* g_ = Wb + (size_t)(c_ * 16 + brow) * 1024 + (T) * 32 + bcol; \
    __builtin_amdgcn_global_load_lds((const __attribute__((address_space(1))) void*)g_, \
        (__attribute__((address_space(3))) void*)&Blds[WB][c_ * 512], 16, 0, 0); } } while (0)

#define ALOAD(T, REG) do { REG = *(const float4*)(aload + (size_t)(T) * 32); } while (0)

#define ACVT(REG, AB) do { \
  uint2 pk_; pk_.x = pack2bf(REG.x, REG.y); pk_.y = pack2bf(REG.z, REG.w); \
  *(uint2*)&Alds[AB][awr] = pk_; } while (0)

#define COMPUTE(RB, AB) do { \
  const u16* Ab_ = Alds[AB]; const u16* Bb_ = Blds[RB]; \
  bf16x8 af_[4], bf_[6]; \
  _Pragma("unroll") for (int mf = 0; mf < 4; ++mf) \
    af_[mf] = *(const bf16x8*)&Ab_[(mf * 16 + lrow) * 32 + sw]; \
  _Pragma("unroll") for (int nf = 0; nf < 6; ++nf) \
    bf_[nf] = *(const bf16x8*)&Bb_[(wid * 96 + nf * 16 + lrow) * 32 + sw]; \
  __builtin_amdgcn_s_setprio(1); \
  _Pragma("unroll") for (int mf = 0; mf < 4; ++mf) \
    _Pragma("unroll") for (int nf = 0; nf < 6; ++nf) \
      acc[mf][nf] = __builtin_amdgcn_mfma_f32_16x16x32_bf16(af_[mf], bf_[nf], acc[mf][nf], 0, 0, 0); \
  __builtin_amdgcn_s_setprio(0); } while (0)

  f32x4 acc[4][6] = {};
  float4 aS0, aS1;

  // ---- prologue: A(0),A(1) loads first (keeps auto-waitcnt minimal), B(0),B(1) ----
  ALOAD(0, aS0); ALOAD(1, aS1);
  BSTAGE(0, 0); BSTAGE(1, 1);
  ACVT(aS0, 0);                                     // compiler waits on aS0 only
  asm volatile("s_waitcnt vmcnt(7)" ::: "memory");  // force B(0); B(1)+A(1) in flight
  asm volatile("s_waitcnt lgkmcnt(0)" ::: "memory");
  __builtin_amdgcn_s_barrier();

  int rb = 0, wb = 2;
  for (int ti = 0; ti < 16; ++ti) {
    const bool pf = ti < 15;
    // ---- even body: t = 2ti  (A read buf 0, A cvt -> buf 1) ----
    if (pf) { ALOAD(2 * ti + 2, aS0); BSTAGE(2 * ti + 2, wb); }
    __builtin_amdgcn_sched_barrier(0);
    COMPUTE(rb, 0);
    __builtin_amdgcn_sched_barrier(0);
    ACVT(aS1, 1);                                   // A(2ti+1), always valid
    if (pf) { asm volatile("s_waitcnt vmcnt(7)" ::: "memory"); }
    else    { asm volatile("s_waitcnt vmcnt(0)" ::: "memory"); }
    asm volatile("s_waitcnt lgkmcnt(0)" ::: "memory");
    __builtin_amdgcn_s_barrier();
    rb = (rb == 2) ? 0 : rb + 1; wb = (wb == 2) ? 0 : wb + 1;
    // ---- odd body: t = 2ti+1 (A read buf 1, A cvt -> buf 0) ----
    if (pf) { ALOAD(2 * ti + 3, aS1); BSTAGE(2 * ti + 3, wb); }
    __builtin_amdgcn_sched_barrier(0);
    COMPUTE(rb, 1);
    __builtin_amdgcn_sched_barrier(0);
    if (pf) {
      ACVT(aS0, 0);                                 // A(2ti+2)
      asm volatile("s_waitcnt vmcnt(7)" ::: "memory");
      asm volatile("s_waitcnt lgkmcnt(0)" ::: "memory");
      __builtin_amdgcn_s_barrier();
    }
    rb = (rb == 2) ? 0 : rb + 1; wb = (wb == 2) ? 0 : wb + 1;
  }

  // ---- epilogue: cols 0..255 -> Q, 256..511 -> K, 512..767 -> V^T ----
#pragma unroll
  for (int mf = 0; mf < 4; ++mf)
#pragma unroll
    for (int nf = 0; nf < 6; ++nf) {
      const int gm = m0 + mf * 16 + lkg * 4;
      const int c = wid * 96 + nf * 16 + lrow;
      if (c < 512) {
        u16* Dst = (c < 256) ? Qb : Kb;
        const int cc = c & 255;
#pragma unroll
        for (int r = 0; r < 4; ++r) Dst[(size_t)(gm + r) * 256 + cc] = f2bf(acc[mf][nf][r]);
      } else {
        const int h = c - 512;
        const int bb = gm >> 12, l = gm & 4095;
        u16x4 pk;
        pk.x = f2bf(acc[mf][nf][0]); pk.y = f2bf(acc[mf][nf][1]);
        pk.z = f2bf(acc[mf][nf][2]); pk.w = f2bf(acc[mf][nf][3]);
        *(u16x4*)&Vt[((size_t)bb * 256 + h) * 4096 + l] = pk;
      }
    }
}

// ---- kernel 2: WINDOWED decay attention ----------------------------------
// gamma^320 ~ 2.5e-15 => keys older than the aligned 256..319 window are
// numerically zero in fp32. QB=32 rows/WG, KB=64, 4 waves (256 thr).
__global__ __launch_bounds__(256) void attn_kernel(const u16* __restrict__ Qb, const u16* __restrict__ Kb,
                                                   const u16* __restrict__ Vt, float* __restrict__ out) {
  __shared__ u16 Plds[32 * 72];
  const int raw = blockIdx.x;                 // 0..511
  const int aid = (raw & 7) * 64 + (raw >> 3);  // XCD-chunked
  const int b = aid >> 7;                     // 0..3
  const int qt = aid & 127;                   // 0..127
  const int qb = qt * 32;
  const int tid = threadIdx.x;
  const int wid = tid >> 6, lane = tid & 63;
  const int lrow = lane & 15, lkg = lane >> 4, lk = lkg * 8;
  const size_t bQK = (size_t)b * 4096 * 256;

  bf16x8 qf[2][8];
#pragma unroll
  for (int mf = 0; mf < 2; ++mf) {
    const u16* Qrow = Qb + bQK + (size_t)(qb + mf * 16 + lrow) * 256;
#pragma unroll
    for (int kf = 0; kf < 8; ++kf) qf[mf][kf] = *(const bf16x8*)&Qrow[kf * 32 + lk];
  }

  int kstart = qb - 256; if (kstart < 0) kstart = 0; kstart &= ~63;
  const int njt = (qb + 32 - kstart + 63) >> 6;

  f32x4 oacc[2][4] = {};

  for (int jt = 0; jt < njt; ++jt) {
    const int kb = kstart + jt * 64;
    f32x4 s[2] = {};
    const u16* Krow = Kb + bQK + (size_t)(kb + wid * 16 + lrow) * 256;
#pragma unroll
    for (int kf = 0; kf < 8; ++kf) {
      const bf16x8 kfr = *(const bf16x8*)&Krow[kf * 32 + lk];
      s[0] = __builtin_amdgcn_mfma_f32_16x16x32_bf16(qf[0][kf], kfr, s[0], 0, 0, 0);
      s[1] = __builtin_amdgcn_mfma_f32_16x16x32_bf16(qf[1][kf], kfr, s[1], 0, 0, 0);
    }
    const int kg = kb + wid * 16 + lrow;
#pragma unroll
    for (int mf = 0; mf < 2; ++mf) {
      const int qg = qb + mf * 16 + lkg * 4;
#pragma unroll
      for (int r = 0; r < 4; ++r) {
        const int d = qg + r - kg;
        const float pv = (d >= 0) ? s[mf][r] * exp2f((float)d * L2GAMMA) * INV_SQRT_H : 0.0f;
        Plds[(mf * 16 + lkg * 4 + r) * 72 + wid * 16 + lrow] = f2bf(pv);
      }
    }
    __syncthreads();
#pragma unroll
    for (int ks = 0; ks < 2; ++ks) {
      bf16x8 pa[2];
      pa[0] = *(const bf16x8*)&Plds[(lrow) * 72 + ks * 32 + lk];
      pa[1] = *(const bf16x8*)&Plds[(16 + lrow) * 72 + ks * 32 + lk];
#pragma unroll
      for (int nf = 0; nf < 4; ++nf) {
        const bf16x8 vb = *(const bf16x8*)&Vt[((size_t)b * 256 + wid * 64 + nf * 16 + lrow) * 4096 + kb + ks * 32 + lk];
        oacc[0][nf] = __builtin_amdgcn_mfma_f32_16x16x32_bf16(pa[0], vb, oacc[0][nf], 0, 0, 0);
        oacc[1][nf] = __builtin_amdgcn_mfma_f32_16x16x32_bf16(pa[1], vb, oacc[1][nf], 0, 0, 0);
      }
    }
    __syncthreads();
  }

#pragma unroll
  for (int mf = 0; mf < 2; ++mf) {
    float* obase = out + ((size_t)b * 4096 + qb + mf * 16 + lkg * 4) * 256 + wid * 64 + lrow;
#pragma unroll
    for (int nf = 0; nf < 4; ++nf)
#pragma unroll
      for (int r = 0; r < 4; ++r)
        obase[(size_t)r * 256 + nf * 16] = oacc[mf][nf][r];
  }
}

extern "C" void kernel_launch(void* const* d_in, const int* in_sizes, int n_in,
                              void* d_out, int out_size, void* d_ws, size_t ws_size,
                              hipStream_t stream) {
  const float* x  = (const float*)d_in[0];
  const float* wq = (const float*)d_in[1];
  const float* wk = (const float*)d_in[2];
  const float* wv = (const float*)d_in[3];
  float* out = (float*)d_out;
  char* ws = (char*)d_ws;
  u16* Wb = (u16*)(ws);                          //   768*1024*2 = 1,572,864
  u16* Qb = (u16*)(ws + (size_t)1572864);        // 16384*256*2  = 8,388,608
  u16* Kb = (u16*)(ws + (size_t)9961472);        //  8,388,608
  u16* Vt = (u16*)(ws + (size_t)18350080);       //  8,388,608  (end 26,738,688)

  hipLaunchKernelGGL(cvt_w_kernel, dim3(768), dim3(256), 0, stream,
                     (const float4*)wq, (const float4*)wk, (const float4*)wv, (u16x4*)Wb);
  hipLaunchKernelGGL(qkv_gemm_kernel, dim3(256), dim3(512), 0, stream, x, Wb, Qb, Kb, Vt);
  hipLaunchKernelGGL(attn_kernel, dim3(512), dim3(256), 0, stream, Qb, Kb, Vt, out);
}

// Round 8
// 76.613 us; speedup vs baseline: 1.1715x; 1.1715x over previous
//
#include <hip/hip_runtime.h>

typedef unsigned short u16;
typedef unsigned int u32;
typedef __attribute__((ext_vector_type(8))) short bf16x8;
typedef __attribute__((ext_vector_type(4))) float f32x4;
typedef __attribute__((ext_vector_type(4))) unsigned short u16x4;

#define DEVI __device__ __forceinline__
#define AS1 __attribute__((address_space(1)))
#define AS3 __attribute__((address_space(3)))

constexpr float L2GAMMA = -0.15200309344504997f; // log2(0.9)
constexpr float INV_SQRT_H = 0.0625f;            // 1/sqrt(256)

DEVI u16 f2bf(float x) {
  union { float f; unsigned u; } v; v.f = x;
  unsigned r = v.u + 0x7FFFu + ((v.u >> 16) & 1u);
  return (u16)(r >> 16);
}

DEVI u32 pack2bf(float f0, float f1) {
  u32 u0 = __float_as_uint(f0) + 0x8000u;
  u32 u1 = __float_as_uint(f1) + 0x8000u;
  return __builtin_amdgcn_perm(u1, u0, 0x07060302u); // [f1.hi16 : f0.hi16]
}

// ---- kernel 0: W_Q|W_K|W_V (each 256x1024 fp32) -> Wb[768][1024] bf16 ----
__global__ void cvt_w_kernel(const float4* __restrict__ wq, const float4* __restrict__ wk,
                             const float4* __restrict__ wv, u16x4* __restrict__ dst) {
  int i = blockIdx.x * blockDim.x + threadIdx.x; // 0..196607
  int w = i >> 16, off = i & 65535;
  const float4* s = (w == 0) ? wq : ((w == 1) ? wk : wv);
  float4 v = s[off];
  u16x4 o; o.x = f2bf(v.x); o.y = f2bf(v.y); o.z = f2bf(v.z); o.w = f2bf(v.w);
  dst[(w << 16) + off] = o;
}

// ---- kernel 1: fused QKV GEMM  C[16384x768] = x[16384x1024](fp32)*Wb^T ---
// m97-exact structure: 128x128 tile, BK=32, 4 waves, 2 plain barriers/iter,
// NO manual waitcnt/sched pins. Grid 768 = 3 WG/CU (cross-WG overlap does
// the latency hiding). LDS 24 KB only: A staged as FP32 via gload_lds
// (16 KB, cvt->bf16 at frag-read), B bf16 (8 KB).
// Swizzles (derived, <=2-way = free):
//   A rows 128 B, 8 slots: phys_slot = slot ^ (row&7)
//   B rows  64 B, 4 slots: phys_slot = slot ^ ((row>>1)&3)
// both realized as pre-swizzled GLOBAL source + linear gload_lds dest.
__global__ __launch_bounds__(256, 3) void qkv_gemm_kernel(const float* __restrict__ Xf, const u16* __restrict__ Wb,
                                                          u16* __restrict__ Qb, u16* __restrict__ Kb,
                                                          u16* __restrict__ Vt) {
  __shared__ float Af[128 * 32];   // fp32 A tile, swizzled slots (16 KB)
  __shared__ u16 Bl[128 * 32];     // bf16 B tile, swizzled slots (8 KB)
  const int lin = blockIdx.x;                     // 0..767
  const int rl = (lin & 7) * 96 + (lin >> 3);     // XCD-chunked bijection
  const int nt = rl % 6;
  const int m0 = (rl / 6) * 128;
  const int n0 = nt * 128;
  const int tid = threadIdx.x;
  const int wid = tid >> 6, lane = tid & 63;
  const int wm = wid >> 1, wn = wid & 1;
  const int lrow = lane & 15, lkg = lane >> 4;
  // A staging: chunk = 8 rows x 128 B; lane -> row lane>>3, slot lane&7
  const int arow_in = lane >> 3;
  const int aslot_src = (lane & 7) ^ arow_in;               // pre-swizzled src slot
  // B staging: chunk = 16 rows x 64 B; lane -> row lane>>2, slot lane&3
  const int brow_in = lane >> 2;
  const int bslot_src = (lane & 3) ^ ((lane >> 3) & 3);

  f32x4 acc[4][4] = {};

  for (int kt = 0; kt < 32; ++kt) {
    const int k0 = kt * 32;
    // ---- stage A (fp32): 16 chunks, 4 per wave ----
#pragma unroll
    for (int r = 0; r < 4; ++r) {
      const int c = wid * 4 + r;                  // 0..15
      const float* g = Xf + (size_t)(m0 + c * 8 + arow_in) * 1024 + k0 + aslot_src * 4;
      __builtin_amdgcn_global_load_lds((const AS1 void*)g, (AS3 void*)&Af[c * 256], 16, 0, 0);
    }
    // ---- stage B (bf16): 8 chunks, 2 per wave ----
#pragma unroll
    for (int r = 0; r < 2; ++r) {
      const int c = wid * 2 + r;                  // 0..7
      const u16* g = Wb + (size_t)(n0 + c * 16 + brow_in) * 1024 + k0 + bslot_src * 8;
      __builtin_amdgcn_global_load_lds((const AS1 void*)g, (AS3 void*)&Bl[c * 512], 16, 0, 0);
    }
    __syncthreads();
    // ---- fragments ----
    bf16x8 a[4], b[4];
#pragma unroll
    for (int mf = 0; mf < 4; ++mf) {
      const int row = wm * 64 + mf * 16 + lrow;
      const int e0 = (2 * lkg) ^ (lrow & 7);      // phys slot of logical slot 2*lkg
      const float4 lo = *(const float4*)&Af[row * 32 + e0 * 4];
      const float4 hi = *(const float4*)&Af[row * 32 + (e0 ^ 1) * 4];
      union { u32 w[4]; bf16x8 v; } ua;
      ua.w[0] = pack2bf(lo.x, lo.y); ua.w[1] = pack2bf(lo.z, lo.w);
      ua.w[2] = pack2bf(hi.x, hi.y); ua.w[3] = pack2bf(hi.z, hi.w);
      a[mf] = ua.v;
    }
#pragma unroll
    for (int nf = 0; nf < 4; ++nf) {
      const int row = wn * 64 + nf * 16 + lrow;
      const int s = lkg ^ ((row >> 1) & 3);
      b[nf] = *(const bf16x8*)&Bl[row * 32 + s * 8];
    }
#pragma unroll
    for (int mf = 0; mf < 4; ++mf)
#pragma unroll
      for (int nf = 0; nf < 4; ++nf)
        acc[mf][nf] = __builtin_amdgcn_mfma_f32_16x16x32_bf16(a[mf], b[nf], acc[mf][nf], 0, 0, 0);
    __syncthreads();
  }

  // ---- epilogue: nt 0,1 -> Q; 2,3 -> K; 4,5 -> V transposed ----
  const int rbase = lkg * 4;
  if (nt < 4) {
    u16* Dst = (nt < 2) ? Qb : Kb;
    const int cb = (nt < 2) ? n0 : (n0 - 256);
#pragma unroll
    for (int mf = 0; mf < 4; ++mf)
#pragma unroll
      for (int nf = 0; nf < 4; ++nf) {
        const int gm = m0 + wm * 64 + mf * 16 + rbase;
        const int c = cb + wn * 64 + nf * 16 + lrow;
#pragma unroll
        for (int r = 0; r < 4; ++r) Dst[(size_t)(gm + r) * 256 + c] = f2bf(acc[mf][nf][r]);
      }
  } else {
#pragma unroll
    for (int mf = 0; mf < 4; ++mf)
#pragma unroll
      for (int nf = 0; nf < 4; ++nf) {
        const int gm = m0 + wm * 64 + mf * 16 + rbase;
        const int h = n0 - 512 + wn * 64 + nf * 16 + lrow;
        const int bb = gm >> 12, l = gm & 4095;
        u16x4 pk;
        pk.x = f2bf(acc[mf][nf][0]); pk.y = f2bf(acc[mf][nf][1]);
        pk.z = f2bf(acc[mf][nf][2]); pk.w = f2bf(acc[mf][nf][3]);
        *(u16x4*)&Vt[((size_t)bb * 256 + h) * 4096 + l] = pk;
      }
  }
}

// ---- kernel 2: WINDOWED decay attention ----------------------------------
// gamma^320 ~ 2.5e-15 => keys older than the aligned 256..319 window are
// numerically zero in fp32. QB=32 rows/WG, KB=64, 4 waves (256 thr).
__global__ __launch_bounds__(256) void attn_kernel(const u16* __restrict__ Qb, const u16* __restrict__ Kb,
                                                   const u16* __restrict__ Vt, float* __restrict__ out) {
  __shared__ u16 Plds[32 * 72];
  const int raw = blockIdx.x;                 // 0..511
  const int aid = (raw & 7) * 64 + (raw >> 3);  // XCD-chunked
  const int b = aid >> 7;                     // 0..3
  const int qt = aid & 127;                   // 0..127
  const int qb = qt * 32;
  const int tid = threadIdx.x;
  const int wid = tid >> 6, lane = tid & 63;
  const int lrow = lane & 15, lkg = lane >> 4, lk = lkg * 8;
  const size_t bQK = (size_t)b * 4096 * 256;

  bf16x8 qf[2][8];
#pragma unroll
  for (int mf = 0; mf < 2; ++mf) {
    const u16* Qrow = Qb + bQK + (size_t)(qb + mf * 16 + lrow) * 256;
#pragma unroll
    for (int kf = 0; kf < 8; ++kf) qf[mf][kf] = *(const bf16x8*)&Qrow[kf * 32 + lk];
  }

  int kstart = qb - 256; if (kstart < 0) kstart = 0; kstart &= ~63;
  const int njt = (qb + 32 - kstart + 63) >> 6;

  f32x4 oacc[2][4] = {};

  for (int jt = 0; jt < njt; ++jt) {
    const int kb = kstart + jt * 64;
    f32x4 s[2] = {};
    const u16* Krow = Kb + bQK + (size_t)(kb + wid * 16 + lrow) * 256;
#pragma unroll
    for (int kf = 0; kf < 8; ++kf) {
      const bf16x8 kfr = *(const bf16x8*)&Krow[kf * 32 + lk];
      s[0] = __builtin_amdgcn_mfma_f32_16x16x32_bf16(qf[0][kf], kfr, s[0], 0, 0, 0);
      s[1] = __builtin_amdgcn_mfma_f32_16x16x32_bf16(qf[1][kf], kfr, s[1], 0, 0, 0);
    }
    const int kg = kb + wid * 16 + lrow;
#pragma unroll
    for (int mf = 0; mf < 2; ++mf) {
      const int qg = qb + mf * 16 + lkg * 4;
#pragma unroll
      for (int r = 0; r < 4; ++r) {
        const int d = qg + r - kg;
        const float pv = (d >= 0) ? s[mf][r] * exp2f((float)d * L2GAMMA) * INV_SQRT_H : 0.0f;
        Plds[(mf * 16 + lkg * 4 + r) * 72 + wid * 16 + lrow] = f2bf(pv);
      }
    }
    __syncthreads();
#pragma unroll
    for (int ks = 0; ks < 2; ++ks) {
      bf16x8 pa[2];
      pa[0] = *(const bf16x8*)&Plds[(lrow) * 72 + ks * 32 + lk];
      pa[1] = *(const bf16x8*)&Plds[(16 + lrow) * 72 + ks * 32 + lk];
#pragma unroll
      for (int nf = 0; nf < 4; ++nf) {
        const bf16x8 vb = *(const bf16x8*)&Vt[((size_t)b * 256 + wid * 64 + nf * 16 + lrow) * 4096 + kb + ks * 32 + lk];
        oacc[0][nf] = __builtin_amdgcn_mfma_f32_16x16x32_bf16(pa[0], vb, oacc[0][nf], 0, 0, 0);
        oacc[1][nf] = __builtin_amdgcn_mfma_f32_16x16x32_bf16(pa[1], vb, oacc[1][nf], 0, 0, 0);
      }
    }
    __syncthreads();
  }

#pragma unroll
  for (int mf = 0; mf < 2; ++mf) {
    float* obase = out + ((size_t)b * 4096 + qb + mf * 16 + lkg * 4) * 256 + wid * 64 + lrow;
#pragma unroll
    for (int nf = 0; nf < 4; ++nf)
#pragma unroll
      for (int r = 0; r < 4; ++r)
        obase[(size_t)r * 256 + nf * 16] = oacc[mf][nf][r];
  }
}

extern "C" void kernel_launch(void* const* d_in, const int* in_sizes, int n_in,
                              void* d_out, int out_size, void* d_ws, size_t ws_size,
                              hipStream_t stream) {
  const float* x  = (const float*)d_in[0];
  const float* wq = (const float*)d_in[1];
  const float* wk = (const float*)d_in[2];
  const float* wv = (const float*)d_in[3];
  float* out = (float*)d_out;
  char* ws = (char*)d_ws;
  u16* Wb = (u16*)(ws);                          //   768*1024*2 = 1,572,864
  u16* Qb = (u16*)(ws + (size_t)1572864);        // 16384*256*2  = 8,388,608
  u16* Kb = (u16*)(ws + (size_t)9961472);        //  8,388,608
  u16* Vt = (u16*)(ws + (size_t)18350080);       //  8,388,608  (end 26,738,688)

  hipLaunchKernelGGL(cvt_w_kernel, dim3(768), dim3(256), 0, stream,
                     (const float4*)wq, (const float4*)wk, (const float4*)wv, (u16x4*)Wb);
  hipLaunchKernelGGL(qkv_gemm_kernel, dim3(768), dim3(256), 0, stream, x, Wb, Qb, Kb, Vt);
  hipLaunchKernelGGL(attn_kernel, dim3(512), dim3(256), 0, stream, Qb, Kb, Vt, out);
}